// Round 3
// baseline (221.430 us; speedup 1.0000x reference)
//
#include <hip/hip_runtime.h>
#include <math.h>

#define D 768
#define DF4 192               // D / 4
#define NQ 128                // total queries
#define KPQ 784               // keys per query
#define NCHUNK 16             // key chunks per query
#define KCHUNK 49             // KPQ / NCHUNK

__device__ __forceinline__ float dot4f(const float4 a, const float4 b) {
    return a.x * b.x + a.y * b.y + a.z * b.z + a.w * b.w;
}

// ---------------------------------------------------------------------------
// Transpose Wq, Wv, Wo (768x768) -> ws.  64x64 tiles, LDS with +1 pad.
// grid (144, 3), 256 threads.
// ---------------------------------------------------------------------------
__global__ __launch_bounds__(256) void k_tr(const float* __restrict__ Wq,
                                            const float* __restrict__ Wv,
                                            const float* __restrict__ Wo,
                                            float* __restrict__ WqT,
                                            float* __restrict__ WvT,
                                            float* __restrict__ WoT) {
    __shared__ float t[64][65];
    const float* src;
    float* dst;
    if (blockIdx.y == 0)      { src = Wq; dst = WqT; }
    else if (blockIdx.y == 1) { src = Wv; dst = WvT; }
    else                      { src = Wo; dst = WoT; }
    const int tr = blockIdx.x / 12, tc = blockIdx.x % 12;
    const int r0 = tr * 64, c0 = tc * 64;
    const int lr = threadIdx.x >> 6, lc = threadIdx.x & 63;
#pragma unroll
    for (int i = 0; i < 16; ++i)
        t[lr + i * 4][lc] = src[(size_t)(r0 + lr + i * 4) * D + c0 + lc];
    __syncthreads();
#pragma unroll
    for (int i = 0; i < 16; ++i)
        dst[(size_t)(c0 + lr + i * 4) * D + r0 + lc] = t[lc][lr + i * 4];
}

// ---------------------------------------------------------------------------
// Generic small GEMM: Out[i][e] = sum_d A[i][d] * W[d][e] (+bias[e]) (+res[i][e])
// Lanes over e -> coalesced W reads; A[i][d] wave-uniform -> s_loads. No LDS.
// grid = (NQ/2)*3 blocks, 256 threads; block covers 2 queries x 256 cols.
// ---------------------------------------------------------------------------
template <bool BIAS, bool RES>
__global__ __launch_bounds__(256) void k_gemm(const float* __restrict__ A,
                                              const float* __restrict__ W,
                                              const float* __restrict__ bias,
                                              const float* __restrict__ resid,
                                              float* __restrict__ Out) {
    const int ct = blockIdx.x % 3;
    const int q0 = (blockIdx.x / 3) * 2;
    const int e  = ct * 256 + threadIdx.x;
    const float* a0 = A + (size_t)q0 * D;
    const float* a1 = a0 + D;
    const float* wp = W + e;
    float acc0 = 0.f, acc1 = 0.f;
#pragma unroll 8
    for (int d = 0; d < D; ++d) {
        const float wv = wp[(size_t)d * D];
        acc0 = fmaf(a0[d], wv, acc0);   // a0[d]: uniform -> scalar load
        acc1 = fmaf(a1[d], wv, acc1);
    }
    if (BIAS) {
        const float b = bias[e];
        acc0 += b; acc1 += b;
    }
    if (RES) {
        acc0 += resid[(size_t)q0 * D + e];
        acc1 += resid[(size_t)(q0 + 1) * D + e];
    }
    Out[(size_t)q0 * D + e]       = acc0;
    Out[(size_t)(q0 + 1) * D + e] = acc1;
}

// ---------------------------------------------------------------------------
// Flash pass: one block per (query, key-chunk of 49).  Branch-free online
// softmax, 2-row unroll per wave.  HR read exactly once.
// ---------------------------------------------------------------------------
__global__ __launch_bounds__(256) void k_flash(const float4* __restrict__ HR,
                                               const float4* __restrict__ qt,
                                               float4* __restrict__ Cpart,
                                               float2* __restrict__ ML) {
    const int b     = blockIdx.x;
    const int qi    = b >> 4;
    const int chunk = b & 15;
    const size_t rowbase = (size_t)qi * KPQ + (size_t)chunk * KCHUNK;
    const int tid  = threadIdx.x;
    const int w    = tid >> 6;
    const int lane = tid & 63;

    const float4 qa = qt[qi * DF4 + lane];
    const float4 qb = qt[qi * DF4 + lane + 64];
    const float4 qc = qt[qi * DF4 + lane + 128];
    const float rsd = 0.036084391824351615f;   // 1/sqrt(768)

    float m = -1e30f, l = 0.f;
    float4 c0 = make_float4(0.f, 0.f, 0.f, 0.f);
    float4 c1 = make_float4(0.f, 0.f, 0.f, 0.f);
    float4 c2 = make_float4(0.f, 0.f, 0.f, 0.f);

    int j = w;
    while (j + 4 < KCHUNK) {
        const float4* rowA = HR + (rowbase + (size_t)j) * DF4;
        const float4* rowB = HR + (rowbase + (size_t)(j + 4)) * DF4;
        const float4 a0 = rowA[lane], a1 = rowA[lane + 64], a2 = rowA[lane + 128];
        const float4 b0 = rowB[lane], b1 = rowB[lane + 64], b2 = rowB[lane + 128];
        float p1 = dot4f(qa, a0) + dot4f(qb, a1) + dot4f(qc, a2);
        float p2 = dot4f(qa, b0) + dot4f(qb, b1) + dot4f(qc, b2);
#pragma unroll
        for (int off = 32; off; off >>= 1) {
            p1 += __shfl_xor(p1, off, 64);
            p2 += __shfl_xor(p2, off, 64);
        }
        p1 *= rsd; p2 *= rsd;
        const float mn = fmaxf(m, fmaxf(p1, p2));
        const float ea = __expf(m - mn);
        const float e1 = __expf(p1 - mn);
        const float e2 = __expf(p2 - mn);
        l = l * ea + e1 + e2;
        c0.x = fmaf(c0.x, ea, fmaf(e1, a0.x, e2 * b0.x));
        c0.y = fmaf(c0.y, ea, fmaf(e1, a0.y, e2 * b0.y));
        c0.z = fmaf(c0.z, ea, fmaf(e1, a0.z, e2 * b0.z));
        c0.w = fmaf(c0.w, ea, fmaf(e1, a0.w, e2 * b0.w));
        c1.x = fmaf(c1.x, ea, fmaf(e1, a1.x, e2 * b1.x));
        c1.y = fmaf(c1.y, ea, fmaf(e1, a1.y, e2 * b1.y));
        c1.z = fmaf(c1.z, ea, fmaf(e1, a1.z, e2 * b1.z));
        c1.w = fmaf(c1.w, ea, fmaf(e1, a1.w, e2 * b1.w));
        c2.x = fmaf(c2.x, ea, fmaf(e1, a2.x, e2 * b2.x));
        c2.y = fmaf(c2.y, ea, fmaf(e1, a2.y, e2 * b2.y));
        c2.z = fmaf(c2.z, ea, fmaf(e1, a2.z, e2 * b2.z));
        c2.w = fmaf(c2.w, ea, fmaf(e1, a2.w, e2 * b2.w));
        m = mn;
        j += 8;
    }
    if (j < KCHUNK) {
        const float4* rowA = HR + (rowbase + (size_t)j) * DF4;
        const float4 a0 = rowA[lane], a1 = rowA[lane + 64], a2 = rowA[lane + 128];
        float p1 = dot4f(qa, a0) + dot4f(qb, a1) + dot4f(qc, a2);
#pragma unroll
        for (int off = 32; off; off >>= 1) p1 += __shfl_xor(p1, off, 64);
        p1 *= rsd;
        const float mn = fmaxf(m, p1);
        const float ea = __expf(m - mn);
        const float e1 = __expf(p1 - mn);
        l = l * ea + e1;
        c0.x = fmaf(c0.x, ea, e1 * a0.x); c0.y = fmaf(c0.y, ea, e1 * a0.y);
        c0.z = fmaf(c0.z, ea, e1 * a0.z); c0.w = fmaf(c0.w, ea, e1 * a0.w);
        c1.x = fmaf(c1.x, ea, e1 * a1.x); c1.y = fmaf(c1.y, ea, e1 * a1.y);
        c1.z = fmaf(c1.z, ea, e1 * a1.z); c1.w = fmaf(c1.w, ea, e1 * a1.w);
        c2.x = fmaf(c2.x, ea, e1 * a2.x); c2.y = fmaf(c2.y, ea, e1 * a2.y);
        c2.z = fmaf(c2.z, ea, e1 * a2.z); c2.w = fmaf(c2.w, ea, e1 * a2.w);
        m = mn;
    }

    __shared__ __align__(16) float4 c_lds[4][DF4];
    __shared__ float m_lds[4], l_lds[4];
    c_lds[w][lane]       = c0;
    c_lds[w][lane + 64]  = c1;
    c_lds[w][lane + 128] = c2;
    if (lane == 0) { m_lds[w] = m; l_lds[w] = l; }
    __syncthreads();

    if (tid < DF4) {
        float M = fmaxf(fmaxf(m_lds[0], m_lds[1]), fmaxf(m_lds[2], m_lds[3]));
        float L = 0.f;
        float4 cc = make_float4(0.f, 0.f, 0.f, 0.f);
#pragma unroll
        for (int p = 0; p < 4; ++p) {
            const float wg = __expf(m_lds[p] - M);
            L += l_lds[p] * wg;
            const float4 cv = c_lds[p][tid];
            cc.x += cv.x * wg; cc.y += cv.y * wg; cc.z += cv.z * wg; cc.w += cv.w * wg;
        }
        Cpart[(size_t)b * DF4 + tid] = cc;
        if (tid == 0) ML[b] = make_float2(M, L);
    }
}

// ---------------------------------------------------------------------------
// Combine NCHUNK partials per query -> normalized context Cn[qi][.]
// ---------------------------------------------------------------------------
__global__ __launch_bounds__(192) void k_combine(const float4* __restrict__ Cpart,
                                                 const float2* __restrict__ ML,
                                                 float4* __restrict__ Cn) {
    const int qi = blockIdx.x;
    const int f  = threadIdx.x;
    float mmax = -1e30f;
    float2 mls[NCHUNK];
#pragma unroll
    for (int p = 0; p < NCHUNK; ++p) {
        mls[p] = ML[qi * NCHUNK + p];
        mmax = fmaxf(mmax, mls[p].x);
    }
    float L = 0.f;
    float4 c = make_float4(0.f, 0.f, 0.f, 0.f);
#pragma unroll
    for (int p = 0; p < NCHUNK; ++p) {
        const float wg = __expf(mls[p].x - mmax);
        L += mls[p].y * wg;
        const float4 v = Cpart[(size_t)(qi * NCHUNK + p) * DF4 + f];
        c.x += v.x * wg; c.y += v.y * wg; c.z += v.z * wg; c.w += v.w * wg;
    }
    const float inv = 1.f / L;
    c.x *= inv; c.y *= inv; c.z *= inv; c.w *= inv;
    Cn[(size_t)qi * DF4 + f] = c;
}

// ---------------------------------------------------------------------------
// LayerNorm: one block per query (256 threads, 3 elems each).
// ---------------------------------------------------------------------------
__global__ __launch_bounds__(256) void k_ln(const float* __restrict__ y,
                                            const float* __restrict__ gamma,
                                            const float* __restrict__ beta,
                                            float* __restrict__ out) {
    __shared__ float sp[4], ssp[4];
    const int qi = blockIdx.x;
    const int tid = threadIdx.x, w = tid >> 6, lane = tid & 63;
    const float* yr = y + (size_t)qi * D;
    const float v0 = yr[tid], v1 = yr[tid + 256], v2 = yr[tid + 512];
    float s  = v0 + v1 + v2;
    float ss = v0 * v0 + v1 * v1 + v2 * v2;
#pragma unroll
    for (int off = 32; off; off >>= 1) {
        s  += __shfl_xor(s, off, 64);
        ss += __shfl_xor(ss, off, 64);
    }
    if (lane == 0) { sp[w] = s; ssp[w] = ss; }
    __syncthreads();
    s  = sp[0] + sp[1] + sp[2] + sp[3];
    ss = ssp[0] + ssp[1] + ssp[2] + ssp[3];
    const float mu  = s * (1.f / 768.f);
    const float var = ss * (1.f / 768.f) - mu * mu;
    const float rs  = rsqrtf(var + 1e-5f);
    float* o = out + (size_t)qi * D;
    o[tid]       = (v0 - mu) * rs * gamma[tid]       + beta[tid];
    o[tid + 256] = (v1 - mu) * rs * gamma[tid + 256] + beta[tid + 256];
    o[tid + 512] = (v2 - mu) * rs * gamma[tid + 512] + beta[tid + 512];
}

extern "C" void kernel_launch(void* const* d_in, const int* in_sizes, int n_in,
                              void* d_out, int out_size, void* d_ws, size_t ws_size,
                              hipStream_t stream) {
    const float* LR    = (const float*)d_in[0];
    const float* HR    = (const float*)d_in[1];
    const float* Wq    = (const float*)d_in[2];
    const float* bq    = (const float*)d_in[3];
    const float* Wk    = (const float*)d_in[4];
    // d_in[5] = bk: unused (adds per-query constant to all scores; softmax-invariant)
    const float* Wv    = (const float*)d_in[6];
    const float* bv    = (const float*)d_in[7];
    const float* Wo    = (const float*)d_in[8];
    const float* bo    = (const float*)d_in[9];
    const float* gamma = (const float*)d_in[10];
    const float* beta  = (const float*)d_in[11];
    float* out = (float*)d_out;

    float* ws = (float*)d_ws;
    float* WqT   = ws;                  // 589824
    float* WvT   = ws + 589824;         // 589824
    float* WoT   = ws + 1179648;        // 589824
    float* qbuf  = ws + 1769472;        // 98304
    float* qtbuf = ws + 1867776;        // 98304
    float* Cpart = ws + 1966080;        // 1572864
    float* ML    = ws + 3538944;        // 4096
    float* Cn    = ws + 3543040;        // 98304
    float* Xbuf  = ws + 3641344;        // 98304
    float* ybuf  = ws + 3739648;        // 98304

    // transpose Wq, Wv, Wo
    k_tr<<<dim3(144, 3), 256, 0, stream>>>(Wq, Wv, Wo, WqT, WvT, WoT);
    // q = LR @ Wq^T + bq
    k_gemm<true, false><<<(NQ / 2) * 3, 256, 0, stream>>>(LR, WqT, bq, nullptr, qbuf);
    // qt = q @ Wk
    k_gemm<false, false><<<(NQ / 2) * 3, 256, 0, stream>>>(qbuf, Wk, nullptr, nullptr, qtbuf);
    // flash pass over HR
    k_flash<<<NQ * NCHUNK, 256, 0, stream>>>((const float4*)HR, (const float4*)qtbuf,
                                             (float4*)Cpart, (float2*)ML);
    // combine chunk partials -> Cn
    k_combine<<<NQ, 192, 0, stream>>>((const float4*)Cpart, (const float2*)ML, (float4*)Cn);
    // X = Cn @ Wv^T + bv
    k_gemm<true, false><<<(NQ / 2) * 3, 256, 0, stream>>>(Cn, WvT, bv, nullptr, Xbuf);
    // y = q + X @ Wo^T + bo
    k_gemm<true, true><<<(NQ / 2) * 3, 256, 0, stream>>>(Xbuf, WoT, bo, qbuf, ybuf);
    // LayerNorm
    k_ln<<<NQ, 256, 0, stream>>>(ybuf, gamma, beta, out);
}

// Round 5
// 104.854 us; speedup vs baseline: 2.1118x; 2.1118x over previous
//
#include <hip/hip_runtime.h>
#include <math.h>

#define D 768
#define DF2 384               // D / 2
#define DF4 192               // D / 4
#define NQ 128                // total queries
#define KPQ 784               // keys per query
#define NCHUNK 16             // key chunks per query
#define KCHUNK 49             // KPQ / NCHUNK

#define EXP2F(x) __builtin_amdgcn_exp2f(x)

__device__ __forceinline__ float dot4f(const float4 a, const float4 b) {
    return a.x * b.x + a.y * b.y + a.z * b.z + a.w * b.w;
}

// ---------------------------------------------------------------------------
// Transpose Wq, Wv, Wo (768x768) -> ws.  64x64 tiles, LDS +1 pad.
// ---------------------------------------------------------------------------
__global__ __launch_bounds__(256) void k_tr(const float* __restrict__ Wq,
                                            const float* __restrict__ Wv,
                                            const float* __restrict__ Wo,
                                            float* __restrict__ WqT,
                                            float* __restrict__ WvT,
                                            float* __restrict__ WoT) {
    __shared__ float t[64][65];
    const float* src;
    float* dst;
    if (blockIdx.y == 0)      { src = Wq; dst = WqT; }
    else if (blockIdx.y == 1) { src = Wv; dst = WvT; }
    else                      { src = Wo; dst = WoT; }
    const int tr = blockIdx.x / 12, tc = blockIdx.x % 12;
    const int r0 = tr * 64, c0 = tc * 64;
    const int lr = threadIdx.x >> 6, lc = threadIdx.x & 63;
#pragma unroll
    for (int i = 0; i < 16; ++i)
        t[lr + i * 4][lc] = src[(size_t)(r0 + lr + i * 4) * D + c0 + lc];
    __syncthreads();
#pragma unroll
    for (int i = 0; i < 16; ++i)
        dst[(size_t)(c0 + lr + i * 4) * D + r0 + lc] = t[lc][lr + i * 4];
}

// ---------------------------------------------------------------------------
// Small GEMM, split-N x split-K:  Out[q][e] = sum_d A[q][d] * W[d][e] (+b)(+res)
// grid = 6 col-tiles(128 cols) x 32 q-groups(Q=4) = 192 blocks, 512 threads.
// Wave ds owns d in [ds*96, ds*96+96); lane owns one float2 column.
// W loads: 512B/wave coalesced.  A loads: wave-uniform -> scalar loads.
// ---------------------------------------------------------------------------
template <bool BIAS, bool RES>
__global__ __launch_bounds__(512) void k_gemm2(const float* __restrict__ A,
                                               const float2* __restrict__ W2,
                                               const float2* __restrict__ bias2,
                                               const float2* __restrict__ res2,
                                               float2* __restrict__ Out2) {
    __shared__ float2 part[8][4][64];
    const int ct  = blockIdx.x % 6;
    const int q0  = (blockIdx.x / 6) * 4;
    const int tid = threadIdx.x;
    const int ds  = __builtin_amdgcn_readfirstlane(tid >> 6);   // wave id 0..7
    const int c2  = tid & 63;
    const int e2  = ct * 64 + c2;
    const float* a0 = A + (size_t)q0 * D;
    const float* a1 = a0 + D;
    const float* a2 = a1 + D;
    const float* a3 = a2 + D;
    float2 acc0 = {0.f, 0.f}, acc1 = {0.f, 0.f}, acc2 = {0.f, 0.f}, acc3 = {0.f, 0.f};
    const int dbase = ds * 96;
#pragma unroll 8
    for (int i = 0; i < 96; ++i) {
        const int d = dbase + i;
        const float2 wv = W2[(size_t)d * DF2 + e2];
        const float x0 = a0[d], x1 = a1[d], x2 = a2[d], x3 = a3[d];
        acc0.x = fmaf(x0, wv.x, acc0.x); acc0.y = fmaf(x0, wv.y, acc0.y);
        acc1.x = fmaf(x1, wv.x, acc1.x); acc1.y = fmaf(x1, wv.y, acc1.y);
        acc2.x = fmaf(x2, wv.x, acc2.x); acc2.y = fmaf(x2, wv.y, acc2.y);
        acc3.x = fmaf(x3, wv.x, acc3.x); acc3.y = fmaf(x3, wv.y, acc3.y);
    }
    part[ds][0][c2] = acc0;
    part[ds][1][c2] = acc1;
    part[ds][2][c2] = acc2;
    part[ds][3][c2] = acc3;
    __syncthreads();
    if (tid < 256) {
        const int q = tid >> 6, c = tid & 63;
        float2 s = {0.f, 0.f};
#pragma unroll
        for (int p = 0; p < 8; ++p) {
            s.x += part[p][q][c].x;
            s.y += part[p][q][c].y;
        }
        if (BIAS) {
            const float2 b = bias2[ct * 64 + c];
            s.x += b.x; s.y += b.y;
        }
        if (RES) {
            const float2 r = res2[(size_t)(q0 + q) * DF2 + ct * 64 + c];
            s.x += r.x; s.y += r.y;
        }
        Out2[(size_t)(q0 + q) * DF2 + ct * 64 + c] = s;
    }
}

// ---------------------------------------------------------------------------
// Flash pass: one block per (query, key-chunk of 49).  Branch-free online
// softmax in base-2 (1/sqrt(d)*log2e folded into q).  HR read exactly once.
// ---------------------------------------------------------------------------
__global__ __launch_bounds__(256) void k_flash(const float4* __restrict__ HR,
                                               const float4* __restrict__ qt,
                                               float4* __restrict__ Cpart,
                                               float2* __restrict__ ML) {
    const int b     = blockIdx.x;
    const int qi    = b >> 4;
    const int chunk = b & 15;
    const size_t rowbase = (size_t)qi * KPQ + (size_t)chunk * KCHUNK;
    const int tid  = threadIdx.x;
    const int w    = tid >> 6;
    const int lane = tid & 63;

    const float rsd2 = 0.036084391824351615f * 1.4426950408889634f; // 1/sqrt(768)*log2e
    float4 qa = qt[qi * DF4 + lane];
    float4 qb = qt[qi * DF4 + lane + 64];
    float4 qc = qt[qi * DF4 + lane + 128];
    qa.x *= rsd2; qa.y *= rsd2; qa.z *= rsd2; qa.w *= rsd2;
    qb.x *= rsd2; qb.y *= rsd2; qb.z *= rsd2; qb.w *= rsd2;
    qc.x *= rsd2; qc.y *= rsd2; qc.z *= rsd2; qc.w *= rsd2;

    float m = -1e30f, l = 0.f;
    float4 c0 = make_float4(0.f, 0.f, 0.f, 0.f);
    float4 c1 = make_float4(0.f, 0.f, 0.f, 0.f);
    float4 c2 = make_float4(0.f, 0.f, 0.f, 0.f);

    int j = w;
    while (j + 4 < KCHUNK) {
        const float4* rowA = HR + (rowbase + (size_t)j) * DF4;
        const float4* rowB = HR + (rowbase + (size_t)(j + 4)) * DF4;
        const float4 a0 = rowA[lane], a1 = rowA[lane + 64], a2 = rowA[lane + 128];
        const float4 b0 = rowB[lane], b1 = rowB[lane + 64], b2 = rowB[lane + 128];
        float p1 = dot4f(qa, a0) + dot4f(qb, a1) + dot4f(qc, a2);
        float p2 = dot4f(qa, b0) + dot4f(qb, b1) + dot4f(qc, b2);
#pragma unroll
        for (int off = 32; off; off >>= 1) {
            p1 += __shfl_xor(p1, off, 64);
            p2 += __shfl_xor(p2, off, 64);
        }
        const float mn = fmaxf(m, fmaxf(p1, p2));
        const float ea = EXP2F(m - mn);
        const float e1 = EXP2F(p1 - mn);
        const float e2 = EXP2F(p2 - mn);
        l = l * ea + e1 + e2;
        c0.x = fmaf(c0.x, ea, fmaf(e1, a0.x, e2 * b0.x));
        c0.y = fmaf(c0.y, ea, fmaf(e1, a0.y, e2 * b0.y));
        c0.z = fmaf(c0.z, ea, fmaf(e1, a0.z, e2 * b0.z));
        c0.w = fmaf(c0.w, ea, fmaf(e1, a0.w, e2 * b0.w));
        c1.x = fmaf(c1.x, ea, fmaf(e1, a1.x, e2 * b1.x));
        c1.y = fmaf(c1.y, ea, fmaf(e1, a1.y, e2 * b1.y));
        c1.z = fmaf(c1.z, ea, fmaf(e1, a1.z, e2 * b1.z));
        c1.w = fmaf(c1.w, ea, fmaf(e1, a1.w, e2 * b1.w));
        c2.x = fmaf(c2.x, ea, fmaf(e1, a2.x, e2 * b2.x));
        c2.y = fmaf(c2.y, ea, fmaf(e1, a2.y, e2 * b2.y));
        c2.z = fmaf(c2.z, ea, fmaf(e1, a2.z, e2 * b2.z));
        c2.w = fmaf(c2.w, ea, fmaf(e1, a2.w, e2 * b2.w));
        m = mn;
        j += 8;
    }
    if (j < KCHUNK) {
        const float4* rowA = HR + (rowbase + (size_t)j) * DF4;
        const float4 a0 = rowA[lane], a1 = rowA[lane + 64], a2 = rowA[lane + 128];
        float p1 = dot4f(qa, a0) + dot4f(qb, a1) + dot4f(qc, a2);
#pragma unroll
        for (int off = 32; off; off >>= 1) p1 += __shfl_xor(p1, off, 64);
        const float mn = fmaxf(m, p1);
        const float ea = EXP2F(m - mn);
        const float e1 = EXP2F(p1 - mn);
        l = l * ea + e1;
        c0.x = fmaf(c0.x, ea, e1 * a0.x); c0.y = fmaf(c0.y, ea, e1 * a0.y);
        c0.z = fmaf(c0.z, ea, e1 * a0.z); c0.w = fmaf(c0.w, ea, e1 * a0.w);
        c1.x = fmaf(c1.x, ea, e1 * a1.x); c1.y = fmaf(c1.y, ea, e1 * a1.y);
        c1.z = fmaf(c1.z, ea, e1 * a1.z); c1.w = fmaf(c1.w, ea, e1 * a1.w);
        c2.x = fmaf(c2.x, ea, e1 * a2.x); c2.y = fmaf(c2.y, ea, e1 * a2.y);
        c2.z = fmaf(c2.z, ea, e1 * a2.z); c2.w = fmaf(c2.w, ea, e1 * a2.w);
        m = mn;
    }

    __shared__ __align__(16) float4 c_lds[4][DF4];
    __shared__ float m_lds[4], l_lds[4];
    c_lds[w][lane]       = c0;
    c_lds[w][lane + 64]  = c1;
    c_lds[w][lane + 128] = c2;
    if (lane == 0) { m_lds[w] = m; l_lds[w] = l; }
    __syncthreads();

    if (tid < DF4) {
        float M = fmaxf(fmaxf(m_lds[0], m_lds[1]), fmaxf(m_lds[2], m_lds[3]));
        float L = 0.f;
        float4 cc = make_float4(0.f, 0.f, 0.f, 0.f);
#pragma unroll
        for (int p = 0; p < 4; ++p) {
            const float wg = EXP2F(m_lds[p] - M);
            L += l_lds[p] * wg;
            const float4 cv = c_lds[p][tid];
            cc.x += cv.x * wg; cc.y += cv.y * wg; cc.z += cv.z * wg; cc.w += cv.w * wg;
        }
        Cpart[(size_t)b * DF4 + tid] = cc;
        if (tid == 0) ML[b] = make_float2(M, L);
    }
}

// ---------------------------------------------------------------------------
// Combine NCHUNK partials per query -> normalized context Cn[qi][.]  (base-2)
// ---------------------------------------------------------------------------
__global__ __launch_bounds__(192) void k_combine(const float4* __restrict__ Cpart,
                                                 const float2* __restrict__ ML,
                                                 float4* __restrict__ Cn) {
    const int qi = blockIdx.x;
    const int f  = threadIdx.x;
    float mmax = -1e30f;
    float2 mls[NCHUNK];
#pragma unroll
    for (int p = 0; p < NCHUNK; ++p) {
        mls[p] = ML[qi * NCHUNK + p];
        mmax = fmaxf(mmax, mls[p].x);
    }
    float L = 0.f;
    float4 c = make_float4(0.f, 0.f, 0.f, 0.f);
#pragma unroll
    for (int p = 0; p < NCHUNK; ++p) {
        const float wg = EXP2F(mls[p].x - mmax);
        L += mls[p].y * wg;
        const float4 v = Cpart[(size_t)(qi * NCHUNK + p) * DF4 + f];
        c.x += v.x * wg; c.y += v.y * wg; c.z += v.z * wg; c.w += v.w * wg;
    }
    const float inv = 1.f / L;
    c.x *= inv; c.y *= inv; c.z *= inv; c.w *= inv;
    Cn[(size_t)qi * DF4 + f] = c;
}

// ---------------------------------------------------------------------------
// LayerNorm: one block per query (256 threads, 3 elems each).
// ---------------------------------------------------------------------------
__global__ __launch_bounds__(256) void k_ln(const float* __restrict__ y,
                                            const float* __restrict__ gamma,
                                            const float* __restrict__ beta,
                                            float* __restrict__ out) {
    __shared__ float sp[4], ssp[4];
    const int qi = blockIdx.x;
    const int tid = threadIdx.x, w = tid >> 6, lane = tid & 63;
    const float* yr = y + (size_t)qi * D;
    const float v0 = yr[tid], v1 = yr[tid + 256], v2 = yr[tid + 512];
    float s  = v0 + v1 + v2;
    float ss = v0 * v0 + v1 * v1 + v2 * v2;
#pragma unroll
    for (int off = 32; off; off >>= 1) {
        s  += __shfl_xor(s, off, 64);
        ss += __shfl_xor(ss, off, 64);
    }
    if (lane == 0) { sp[w] = s; ssp[w] = ss; }
    __syncthreads();
    s  = sp[0] + sp[1] + sp[2] + sp[3];
    ss = ssp[0] + ssp[1] + ssp[2] + ssp[3];
    const float mu  = s * (1.f / 768.f);
    const float var = ss * (1.f / 768.f) - mu * mu;
    const float rs  = rsqrtf(var + 1e-5f);
    float* o = out + (size_t)qi * D;
    o[tid]       = (v0 - mu) * rs * gamma[tid]       + beta[tid];
    o[tid + 256] = (v1 - mu) * rs * gamma[tid + 256] + beta[tid + 256];
    o[tid + 512] = (v2 - mu) * rs * gamma[tid + 512] + beta[tid + 512];
}

extern "C" void kernel_launch(void* const* d_in, const int* in_sizes, int n_in,
                              void* d_out, int out_size, void* d_ws, size_t ws_size,
                              hipStream_t stream) {
    const float* LR    = (const float*)d_in[0];
    const float* HR    = (const float*)d_in[1];
    const float* Wq    = (const float*)d_in[2];
    const float* bq    = (const float*)d_in[3];
    const float* Wk    = (const float*)d_in[4];
    // d_in[5] = bk: unused (per-query constant on all scores; softmax-invariant)
    const float* Wv    = (const float*)d_in[6];
    const float* bv    = (const float*)d_in[7];
    const float* Wo    = (const float*)d_in[8];
    const float* bo    = (const float*)d_in[9];
    const float* gamma = (const float*)d_in[10];
    const float* beta  = (const float*)d_in[11];
    float* out = (float*)d_out;

    float* ws = (float*)d_ws;
    float* WqT   = ws;                  // 589824
    float* WvT   = ws + 589824;         // 589824
    float* WoT   = ws + 1179648;        // 589824
    float* qbuf  = ws + 1769472;        // 98304
    float* qtbuf = ws + 1867776;        // 98304
    float* Cpart = ws + 1966080;        // 1572864
    float* ML    = ws + 3538944;        // 4096
    float* Cn    = ws + 3543040;        // 98304
    float* Xbuf  = ws + 3641344;        // 98304
    float* ybuf  = ws + 3739648;        // 98304

    // transpose Wq, Wv, Wo
    k_tr<<<dim3(144, 3), 256, 0, stream>>>(Wq, Wv, Wo, WqT, WvT, WoT);
    // q = LR @ Wq^T + bq
    k_gemm2<true, false><<<192, 512, 0, stream>>>(LR, (const float2*)WqT,
                                                  (const float2*)bq, nullptr,
                                                  (float2*)qbuf);
    // qt = q @ Wk   (Wk used directly, [d][e] layout)
    k_gemm2<false, false><<<192, 512, 0, stream>>>(qbuf, (const float2*)Wk,
                                                   nullptr, nullptr,
                                                   (float2*)qtbuf);
    // flash pass over HR
    k_flash<<<NQ * NCHUNK, 256, 0, stream>>>((const float4*)HR, (const float4*)qtbuf,
                                             (float4*)Cpart, (float2*)ML);
    // combine chunk partials -> Cn
    k_combine<<<NQ, 192, 0, stream>>>((const float4*)Cpart, (const float2*)ML, (float4*)Cn);
    // X = Cn @ Wv^T + bv
    k_gemm2<true, false><<<192, 512, 0, stream>>>(Cn, (const float2*)WvT,
                                                  (const float2*)bv, nullptr,
                                                  (float2*)Xbuf);
    // y = q + X @ Wo^T + bo
    k_gemm2<true, true><<<192, 512, 0, stream>>>(Xbuf, (const float2*)WoT,
                                                 (const float2*)bo, (const float2*)qbuf,
                                                 (float2*)ybuf);
    // LayerNorm
    k_ln<<<NQ, 256, 0, stream>>>(ybuf, gamma, beta, out);
}